// Round 2
// baseline (60.627 us; speedup 1.0000x reference)
//
#include <hip/hip_runtime.h>

#define BB 64
#define NN 32
#define IND 128
#define HD 512
#define OD 256
#define NPERM 992

typedef __attribute__((ext_vector_type(8))) _Float16 half8;
typedef __attribute__((ext_vector_type(4))) _Float16 half4;
typedef __attribute__((ext_vector_type(16))) float f32x16;

__device__ __forceinline__ half8 relu8(half8 x) {
    half8 z = 0;
    return __builtin_elementwise_max(x, z);
}

// ================= prep: one kernel, 320 blocks x 512 threads, 2 blocks/CU =================
// blocks 0..255  : U' = x@W1a + b1 (g<2) / V = x@W1b (g>=2), 256-h slice, self-contained:
//                  stage x (f32->f16) + W1 slice (f32->f16 transposed, 4x4 micro-transpose)
//                  into padded LDS (row stride 272B), then 8x MFMA 32x32x16.
// blocks 256..319: W2 [512,512] f32 -> W2t [c][k] f16 (transposed) + out init = NPERM*b3.
#define XTO 69632  // xt offset in smem (256*272)
__global__ __launch_bounds__(512, 4) void kprep(
    const float* __restrict__ x, const float* __restrict__ W1, const float* __restrict__ b1,
    const float* __restrict__ W2, _Float16* __restrict__ W2t,
    const float* __restrict__ b3, float* __restrict__ out,
    _Float16* __restrict__ U, _Float16* __restrict__ Vo) {
    __shared__ char smem[(256 + 32) * 272];  // 78336 B (union: w1t+xt / f32 transpose tile)
    const int bid = blockIdx.x;
    const int t = threadIdx.x;

    if (bid >= 256) {
        // ---- W2 transpose + out init ----
        const int bid2 = bid - 256;
        float (*tile)[65] = (float (*)[65])smem;
        if (t < 256) out[(size_t)bid2 * OD + t] = (float)NPERM * b3[t];
        const int k0 = (bid2 & 7) * 64, c0 = (bid2 >> 3) * 64;
        const int cin = t & 63, r0 = (t >> 6) * 8;
#pragma unroll
        for (int rr = 0; rr < 8; ++rr)
            tile[r0 + rr][cin] = W2[(size_t)(k0 + r0 + rr) * HD + c0 + cin];
        __syncthreads();
        const int kout = t & 63;
#pragma unroll
        for (int rr = 0; rr < 8; ++rr) {
            int c = r0 + rr;
            W2t[(size_t)(c0 + c) * HD + k0 + kout] = (_Float16)tile[kout][c];
        }
        return;
    }

    const int g = bid & 3, b = bid >> 2;
    const int h0 = (g & 1) * 256;     // output h-col base
    const int koff = (g >> 1) * 128;  // 0 = W1a (U), 128 = W1b (V)

    // ---- stage x[b] -> xt f16 [32][128], padded rows ----
    {
        const int n = t >> 4, c8 = (t & 15) * 8;
        const float* src = x + ((size_t)(b * NN + n)) * IND + c8;
        float4 f0 = *(const float4*)src;
        float4 f1 = *(const float4*)(src + 4);
        half8 h;
        h[0] = (_Float16)f0.x; h[1] = (_Float16)f0.y;
        h[2] = (_Float16)f0.z; h[3] = (_Float16)f0.w;
        h[4] = (_Float16)f1.x; h[5] = (_Float16)f1.y;
        h[6] = (_Float16)f1.z; h[7] = (_Float16)f1.w;
        *(half8*)(smem + XTO + n * 272 + c8 * 2) = h;
    }
    // ---- stage W1 slice -> w1t f16 [256 h][128 k] transposed, 4x4 micro-transpose ----
    {
        const int ht = t & 63, ktb = t >> 6;
#pragma unroll
        for (int it = 0; it < 4; ++it) {
            const int kt = ktb + it * 8;  // 0..31
            const float* wsrc = W1 + (size_t)(koff + kt * 4) * HD + h0 + ht * 4;
            float4 v0 = *(const float4*)(wsrc);
            float4 v1 = *(const float4*)(wsrc + HD);
            float4 v2 = *(const float4*)(wsrc + 2 * HD);
            float4 v3 = *(const float4*)(wsrc + 3 * HD);
            char* wdst = smem + (size_t)(ht * 4) * 272 + kt * 8;
            half4 o0 = {(_Float16)v0.x, (_Float16)v1.x, (_Float16)v2.x, (_Float16)v3.x};
            half4 o1 = {(_Float16)v0.y, (_Float16)v1.y, (_Float16)v2.y, (_Float16)v3.y};
            half4 o2 = {(_Float16)v0.z, (_Float16)v1.z, (_Float16)v2.z, (_Float16)v3.z};
            half4 o3 = {(_Float16)v0.w, (_Float16)v1.w, (_Float16)v2.w, (_Float16)v3.w};
            *(half4*)(wdst) = o0;
            *(half4*)(wdst + 272) = o1;
            *(half4*)(wdst + 544) = o2;
            *(half4*)(wdst + 816) = o3;
        }
    }
    __syncthreads();

    // ---- MFMA: wave wv owns 32 h-cols ----
    const int lane = t & 63, wv = t >> 6;
    const int l31 = lane & 31, hi = lane >> 5;
    const char* abase = smem + XTO + (size_t)l31 * 272 + hi * 16;
    const char* bbase = smem + (size_t)(wv * 32 + l31) * 272 + hi * 16;

    f32x16 acc;
#pragma unroll
    for (int r = 0; r < 16; ++r) acc[r] = 0.f;
#pragma unroll
    for (int ks = 0; ks < 8; ++ks) {
        half8 a  = *(const half8*)(abase + ks * 32);
        half8 bf = *(const half8*)(bbase + ks * 32);
        acc = __builtin_amdgcn_mfma_f32_32x32x16_f16(a, bf, acc, 0, 0, 0);
    }
    // C layout: col = lane&31 (h), row = (r&3)+8*(r>>2)+4*hi (n)
    const int hglob = h0 + wv * 32 + l31;
    const float bias = (g < 2) ? b1[hglob] : 0.f;
    _Float16* dst = ((g < 2) ? U : Vo) + (size_t)b * NN * HD + hglob;
#pragma unroll
    for (int r = 0; r < 16; ++r) {
        int row = (r & 3) + 8 * (r >> 2) + 4 * hi;
        dst[(size_t)row * HD] = (_Float16)(acc[r] + bias);
    }
}

// ================= main: 256 blocks (8 cb x 32 bp), one round, b-paired =================
// B (W2t 64-col panel, full k=512) resident in LDS, swizzled, reused for both b's.
// U/V stream in 128-k chunks through a 2x16KB double buffer: issue global loads for
// chunk c+1 -> compute 8 ks on chunk c -> ds_write c+1 -> barrier. MFMA hides staging.
// Epilogue per b: masked col-sums -> LDS reduce -> 64x256 GEMV vs W3 -> atomicAdd.
#define UVO 65536
__global__ __launch_bounds__(512, 2) void k2(
    const _Float16* __restrict__ Ug, const _Float16* __restrict__ Vg,
    const _Float16* __restrict__ W2t, const float* __restrict__ b2,
    const float* __restrict__ W3, float* __restrict__ out) {
    __shared__ char smb[65536 + 32768];  // B 64KB + UV dbuf 2x16KB
    __shared__ float red[8][64];
    __shared__ float hred[64];

    const int bp = blockIdx.y;          // b-pair: b = bp*2 + bi
    const int cb0 = blockIdx.x * 64;
    const int t = threadIdx.x;
    const int lane = t & 63, wid = t >> 6;
    const int l31 = lane & 31, hi = lane >> 5;
    const unsigned sw = (unsigned)((l31 & 15) << 4);

    // ---- stage B (full 64 rows x 512 k, swizzled rows of 1024B) ----
    {
        const _Float16* bsrc = W2t + (size_t)cb0 * HD;
#pragma unroll
        for (int ii = 0; ii < 8; ++ii) {
            int id = t + ii * 512;
            int r = id >> 6, m = id & 63;
            uint4 w = *(const uint4*)(bsrc + (size_t)r * HD + m * 8);
            *(uint4*)(smb + (unsigned)(r * 1024 + ((m * 16) ^ ((r & 15) << 4)))) = w;
        }
    }
    // ---- stage UV chunk 0 (b0) ----
    const int rs = t >> 4, ms = t & 15;
    const unsigned dV = (unsigned)(rs * 256 + ((ms * 16) ^ ((rs & 15) << 4)));
    const unsigned dU = (unsigned)(8192 + t * 16);
    {
        uint4 v0 = *(const uint4*)(Vg + (size_t)(bp * 2 * NN + rs) * HD + ms * 8);
        uint4 u0 = *(const uint4*)(Ug + (size_t)(bp * 2 * NN + rs) * HD + ms * 8);
        *(uint4*)(smb + UVO + dV) = v0;
        *(uint4*)(smb + UVO + dU) = u0;
    }
    __syncthreads();

#pragma unroll
    for (int bi = 0; bi < 2; ++bi) {
        f32x16 acc[4][2];
#pragma unroll
        for (int rf = 0; rf < 4; ++rf)
#pragma unroll
            for (int cf = 0; cf < 2; ++cf)
#pragma unroll
                for (int r = 0; r < 16; ++r) acc[rf][cf][r] = 0.f;

#pragma unroll
        for (int c = 0; c < 4; ++c) {
            const int cc = bi * 4 + c;
            const unsigned par = (unsigned)((cc & 1) * 16384);

            // issue next-chunk UV global loads (latency hides under MFMA below)
            uint4 nv, nu;
            const int ncc = cc + 1;
            if (ncc < 8) {
                const int nbi = ncc >> 2, nc = ncc & 3;
                nv = *(const uint4*)(Vg + (size_t)((bp * 2 + nbi) * NN + rs) * HD + nc * 128 + ms * 8);
                nu = *(const uint4*)(Ug + (size_t)((bp * 2 + nbi) * NN + rs) * HD + nc * 128 + ms * 8);
            }

            // ---- compute 8 ks on chunk cc ----
            const unsigned ub = UVO + par + 8192 + (unsigned)(wid * 4) * 256 + hi * 16;
            const unsigned vb = UVO + par + (unsigned)l31 * 256;
            const unsigned b0b = (unsigned)(l31 * 1024 + c * 256);
            const unsigned b1b = (unsigned)((32 + l31) * 1024 + c * 256);

            half8 pU0, pU1, pU2, pU3, pV, pB0, pB1;
            {
                unsigned kx = ((unsigned)(hi * 16)) ^ sw;
                pU0 = *(const half8*)(smb + ub + 0 * 256);
                pU1 = *(const half8*)(smb + ub + 1 * 256);
                pU2 = *(const half8*)(smb + ub + 2 * 256);
                pU3 = *(const half8*)(smb + ub + 3 * 256);
                pV  = *(const half8*)(smb + vb + kx);
                pB0 = *(const half8*)(smb + b0b + kx);
                pB1 = *(const half8*)(smb + b1b + kx);
            }
#pragma unroll
            for (int ks = 0; ks < 8; ++ks) {
                half8 cU0 = pU0, cU1 = pU1, cU2 = pU2, cU3 = pU3;
                half8 cV = pV, cB0 = pB0, cB1 = pB1;
                if (ks < 7) {
                    int kn = ks + 1;
                    unsigned kx = ((unsigned)(kn * 32 + hi * 16)) ^ sw;
                    pU0 = *(const half8*)(smb + ub + 0 * 256 + kn * 32);
                    pU1 = *(const half8*)(smb + ub + 1 * 256 + kn * 32);
                    pU2 = *(const half8*)(smb + ub + 2 * 256 + kn * 32);
                    pU3 = *(const half8*)(smb + ub + 3 * 256 + kn * 32);
                    pV  = *(const half8*)(smb + vb + kx);
                    pB0 = *(const half8*)(smb + b0b + kx);
                    pB1 = *(const half8*)(smb + b1b + kx);
                }

                half8 af0 = relu8(cU0 + cV);
                half8 af1 = relu8(cU1 + cV);
                half8 af2 = relu8(cU2 + cV);
                half8 af3 = relu8(cU3 + cV);

                __builtin_amdgcn_s_setprio(1);
                acc[0][0] = __builtin_amdgcn_mfma_f32_32x32x16_f16(af0, cB0, acc[0][0], 0, 0, 0);
                acc[0][1] = __builtin_amdgcn_mfma_f32_32x32x16_f16(af0, cB1, acc[0][1], 0, 0, 0);
                acc[1][0] = __builtin_amdgcn_mfma_f32_32x32x16_f16(af1, cB0, acc[1][0], 0, 0, 0);
                acc[1][1] = __builtin_amdgcn_mfma_f32_32x32x16_f16(af1, cB1, acc[1][1], 0, 0, 0);
                acc[2][0] = __builtin_amdgcn_mfma_f32_32x32x16_f16(af2, cB0, acc[2][0], 0, 0, 0);
                acc[2][1] = __builtin_amdgcn_mfma_f32_32x32x16_f16(af2, cB1, acc[2][1], 0, 0, 0);
                acc[3][0] = __builtin_amdgcn_mfma_f32_32x32x16_f16(af3, cB0, acc[3][0], 0, 0, 0);
                acc[3][1] = __builtin_amdgcn_mfma_f32_32x32x16_f16(af3, cB1, acc[3][1], 0, 0, 0);
                __builtin_amdgcn_s_setprio(0);
            }

            // ---- write next chunk into the other buffer ----
            if (ncc < 8) {
                const unsigned npar = (unsigned)((ncc & 1) * 16384);
                *(uint4*)(smb + UVO + npar + dV) = nv;
                *(uint4*)(smb + UVO + npar + dU) = nu;
            }
            __syncthreads();
        }

        // ---- epilogue for b = bp*2 + bi ----
        float scf[2];
#pragma unroll
        for (int cf = 0; cf < 2; ++cf) {
            int col = cb0 + cf * 32 + l31;
            float b2v = b2[col];
            float s = 0.f;
#pragma unroll
            for (int rf = 0; rf < 4; ++rf) {
                int i_idx = wid * 4 + rf;
#pragma unroll
                for (int r = 0; r < 16; ++r) {
                    int row = (r & 3) + 8 * (r >> 2) + 4 * hi;  // j index
                    float h2 = fmaxf(acc[rf][cf][r] + b2v, 0.f);
                    if (row != i_idx) s += h2;  // mask i==j
                }
            }
            s += __shfl_xor(s, 32);
            scf[cf] = s;
        }
        if (lane < 32) {
            red[wid][l31] = scf[0];
            red[wid][32 + l31] = scf[1];
        }
        __syncthreads();

        if (t < 64) {
            float hsum = 0.f;
#pragma unroll
            for (int w = 0; w < 8; ++w) hsum += red[w][t];
            hred[t] = hsum;
        }
        __syncthreads();

        {
            int o = t & 255, gg = t >> 8;
            const float* w3p = W3 + ((size_t)(cb0 + gg * 32)) * OD + o;
            float a = 0.f;
#pragma unroll 8
            for (int j = 0; j < 32; ++j)
                a += hred[gg * 32 + j] * w3p[(size_t)j * OD];
            atomicAdd(&out[(size_t)(bp * 2 + bi) * OD + o], a);
        }
    }
}

extern "C" void kernel_launch(void* const* d_in, const int* in_sizes, int n_in,
                              void* d_out, int out_size, void* d_ws, size_t ws_size,
                              hipStream_t stream) {
    const float* x  = (const float*)d_in[0];
    const float* W1 = (const float*)d_in[1];
    const float* b1 = (const float*)d_in[2];
    const float* W2 = (const float*)d_in[3];
    const float* b2 = (const float*)d_in[4];
    const float* W3 = (const float*)d_in[5];
    const float* b3 = (const float*)d_in[6];
    float* out = (float*)d_out;

    _Float16* U   = (_Float16*)d_ws;                    // 2MB  (U' = xW1a + b1, f16)
    _Float16* V   = U + (size_t)BB * NN * HD;           // 2MB  (V  = xW1b, f16)
    _Float16* W2t = V + (size_t)BB * NN * HD;           // 512KB f16 [c][k]

    hipLaunchKernelGGL(kprep, dim3(320), dim3(512), 0, stream,
                       x, W1, b1, W2, W2t, b3, out, U, V);
    hipLaunchKernelGGL(k2, dim3(8, 32), dim3(512), 0, stream, U, V, W2t, b2, W3, out);
}